// Round 3
// baseline (857.049 us; speedup 1.0000x reference)
//
#include <hip/hip_runtime.h>
#include <hip/hip_bf16.h>

// TuckerLinear: out = ((x[:,iperm] @ W^T)[:,oinv]) * alpha * pds + bias
// W = (fo0 (x) fo1 (x) fo2) . G . (fi0 (x) fi1 (x) fi2)^T, G = core as 512x512.
//
// v4 (DIAGNOSTIC round):
//  - kA body repeated x4 in-kernel (idempotent), kG body repeated x6 in-kernel
//    (idempotent) so both dispatches exceed the ~90us harness fills and surface
//    in the rocprof top-5 WITH counters. True per-kernel cost = dur/REP.
//  - kG gains a bijective XCD-aware block swizzle: each XCD owns a contiguous
//    1/8 chunk of the m-fastest grid -> 2 Bm panels (512 KiB) resident per XCD L2.
// Requires ws_size >= 12 MiB.

#define DIN 4096
#define DOUT 4096
#define REP_A 4
#define REP_G 6

typedef __bf16 bf16x8 __attribute__((ext_vector_type(8)));
typedef float f32x4 __attribute__((ext_vector_type(4)));

static __device__ __forceinline__ unsigned int f2bf(float f) {
    unsigned int u = __builtin_bit_cast(unsigned int, f);
    u += 0x7fffu + ((u >> 16) & 1u);     // round-to-nearest-even
    return u >> 16;
}

static __device__ __forceinline__ void gld16(const void* g, void* l) {
    __builtin_amdgcn_global_load_lds(
        (const __attribute__((address_space(1))) void*)g,
        (__attribute__((address_space(3))) void*)l, 16, 0, 0);
}

// ---------------------------------------------------------------------------
// kP: Bm[4096][512] bf16. 128 blocks, each owns 4 k-columns. 3-mode expansion
// of G's k-slice 512 -> 4096 rows in LDS, then row-gather by oinv + scale.
// ---------------------------------------------------------------------------
__global__ __launch_bounds__(256) void tucker_kP(
    const float* __restrict__ G,      // core as [512][512], row g=(a,b,c), col k=(d,e,f)
    const float* __restrict__ fo0,
    const float* __restrict__ fo1,
    const float* __restrict__ fo2,
    const float* __restrict__ pds,
    const float* __restrict__ alpha,
    const int*   __restrict__ oinv,
    unsigned short* __restrict__ Bm)  // ws: [4096][512] bf16
{
    __shared__ float Gk[512 * 4];     //  8 KB  [g][kk]
    __shared__ float W1[1024 * 4];    // 16 KB  [A*64+bc][kk]
    __shared__ float W2[2048 * 4];    // 32 KB  [(A*16+B)*8+c][kk]
    __shared__ float W3[4096 * 4];    // 64 KB  [o'][kk],  o' = A*256+B*16+C
    __shared__ float fos[3 * 128];
    const int t = threadIdx.x;
    const int k0 = blockIdx.x * 4;

    if (t < 128) {
        fos[t]       = fo0[t];
        fos[128 + t] = fo1[t];
        fos[256 + t] = fo2[t];
    }
#pragma unroll
    for (int i = 0; i < 2; ++i) {
        const int g = t + 256 * i;
        *(float4*)(Gk + g * 4) = *(const float4*)(G + (size_t)g * 512 + k0);
    }
    __syncthreads();

    // W1[A][bc] = sum_a fo0[A,a] * Gk[a*64+bc]
#pragma unroll
    for (int i = 0; i < 4; ++i) {
        const int o = t + 256 * i;            // 0..1023
        const int A = o >> 6, bc = o & 63;
        float4 acc = make_float4(0.f, 0.f, 0.f, 0.f);
#pragma unroll
        for (int a = 0; a < 8; ++a) {
            const float f = fos[A * 8 + a];
            const float4 g4 = *(const float4*)(Gk + (a * 64 + bc) * 4);
            acc.x += f * g4.x; acc.y += f * g4.y; acc.z += f * g4.z; acc.w += f * g4.w;
        }
        *(float4*)(W1 + o * 4) = acc;
    }
    __syncthreads();

    // W2[(A*16+B)*8+c] = sum_b fo1[B,b] * W1[A*64 + b*8 + c]
#pragma unroll
    for (int i = 0; i < 8; ++i) {
        const int o = t + 256 * i;            // 0..2047
        const int A = o >> 7, B = (o >> 3) & 15, c = o & 7;
        float4 acc = make_float4(0.f, 0.f, 0.f, 0.f);
#pragma unroll
        for (int b = 0; b < 8; ++b) {
            const float f = fos[128 + B * 8 + b];
            const float4 g4 = *(const float4*)(W1 + (A * 64 + b * 8 + c) * 4);
            acc.x += f * g4.x; acc.y += f * g4.y; acc.z += f * g4.z; acc.w += f * g4.w;
        }
        *(float4*)(W2 + o * 4) = acc;
    }
    __syncthreads();

    // W3[A*256+B*16+C] = sum_c fo2[C,c] * W2[(A*16+B)*8+c]
#pragma unroll
    for (int i = 0; i < 16; ++i) {
        const int o = t + 256 * i;            // 0..4095
        const int A = o >> 8, B = (o >> 4) & 15, C = o & 15;
        float4 acc = make_float4(0.f, 0.f, 0.f, 0.f);
#pragma unroll
        for (int c = 0; c < 8; ++c) {
            const float f = fos[256 + C * 8 + c];
            const float4 g4 = *(const float4*)(W2 + ((A * 16 + B) * 8 + c) * 4);
            acc.x += f * g4.x; acc.y += f * g4.y; acc.z += f * g4.z; acc.w += f * g4.w;
        }
        *(float4*)(W3 + o * 4) = acc;
    }
    __syncthreads();

    const float alf = alpha[0];
#pragma unroll
    for (int i = 0; i < 16; ++i) {
        const int j = t + 256 * i;
        const float s = alf * pds[j];
        const float4 v = *(const float4*)(W3 + (size_t)oinv[j] * 4);
        uint2 pk;
        pk.x = f2bf(v.x * s) | (f2bf(v.y * s) << 16);
        pk.y = f2bf(v.z * s) | (f2bf(v.w * s) << 16);
        *(uint2*)(Bm + (size_t)j * 512 + k0) = pk;
    }
}

// ---------------------------------------------------------------------------
// kA: per-row x-gather + fi contractions -> t3 (bf16) into ws.
// DIAGNOSTIC: whole body repeated REP_A times (idempotent).
// ---------------------------------------------------------------------------
__global__ __launch_bounds__(256) void tucker_kA(
    const float* __restrict__ x,
    const int*   __restrict__ iperm,
    const float* __restrict__ fi0,
    const float* __restrict__ fi1,
    const float* __restrict__ fi2,
    unsigned short* __restrict__ t3o)  // ws: [nrows][512] bf16
{
    __shared__ float xs[4096];         // 16 KB staged x row
    __shared__ float t1[8 * 272];      // [d][E*16+F], d-stride 272 -> 2-way (free)
    __shared__ float t2[8 * 136];      // [d*136 + e*17 + F] -> 2-way (free)
    const int t = threadIdx.x;
    const int n = blockIdx.x;

    for (int rep = 0; rep < REP_A; ++rep) {
    {
        const float4* x4 = (const float4*)(x + (size_t)n * DIN);
        float4* xs4 = (float4*)xs;
#pragma unroll
        for (int i = 0; i < 4; ++i) xs4[t + 256 * i] = x4[t + 256 * i];
    }
    __syncthreads();

    // phase 1: t1[d,E,F] = sum_D xs[perm[D,E,F]] * fi0[D,d]   (t = E*16+F)
    {
        float acc[8];
#pragma unroll
        for (int d = 0; d < 8; ++d) acc[d] = 0.f;
#pragma unroll 4
        for (int D = 0; D < 16; ++D) {
            const int pg = iperm[D * 256 + t];
            const float v = xs[pg];
#pragma unroll
            for (int d = 0; d < 8; ++d) acc[d] += v * fi0[D * 8 + d];
        }
#pragma unroll
        for (int d = 0; d < 8; ++d) t1[d * 272 + t] = acc[d];
    }
    __syncthreads();

    // phase 2: t2[d,e,F] = sum_E t1[d,E,F] * fi1[E,e]
    if (t < 128) {
        const int d = t >> 4, F = t & 15;
        float acc[8];
#pragma unroll
        for (int e = 0; e < 8; ++e) acc[e] = 0.f;
#pragma unroll 4
        for (int E = 0; E < 16; ++E) {
            const float v = t1[d * 272 + E * 16 + F];
#pragma unroll
            for (int e = 0; e < 8; ++e) acc[e] += v * fi1[E * 8 + e];
        }
#pragma unroll
        for (int e = 0; e < 8; ++e) t2[d * 136 + e * 17 + F] = acc[e];
    }
    __syncthreads();

    // phase 3: t3[d,e,f] = sum_F t2[d,e,F] * fi2[F,f]; write bf16-packed
    if (t < 64) {
        const int d = t >> 3, e = t & 7;
        float acc[8];
#pragma unroll
        for (int f = 0; f < 8; ++f) acc[f] = 0.f;
#pragma unroll 4
        for (int F = 0; F < 16; ++F) {
            const float v = t2[d * 136 + e * 17 + F];
#pragma unroll
            for (int f = 0; f < 8; ++f) acc[f] += v * fi2[F * 8 + f];
        }
        uint4 pk;
        pk.x = f2bf(acc[0]) | (f2bf(acc[1]) << 16);
        pk.y = f2bf(acc[2]) | (f2bf(acc[3]) << 16);
        pk.z = f2bf(acc[4]) | (f2bf(acc[5]) << 16);
        pk.w = f2bf(acc[6]) | (f2bf(acc[7]) << 16);
        *(uint4*)(t3o + (size_t)n * 512 + t * 8) = pk;
    }
    __syncthreads();   // protect LDS reuse across reps
    }
}

// ---------------------------------------------------------------------------
// kG: out[M][4096] = t3[M][512] @ Bm[4096][512]^T + bias.
// BM=128, BN=256, BK=64, 512 threads (8 waves, 2m x 4n, 64x64 wave tiles).
// Ring-3 LDS pipeline, counted s_waitcnt vmcnt(6), XOR-swizzled ds_read_b128.
// XCD-aware bijective swizzle: XCD x owns contiguous chunk [x*128, x*128+128)
// of the m-fastest grid -> 2 Bm panels per XCD L2.
// DIAGNOSTIC: whole body repeated REP_G times (idempotent).
// ---------------------------------------------------------------------------
__global__ __launch_bounds__(512) void tucker_kG(
    const unsigned short* __restrict__ A,   // t3 [M][512]
    const unsigned short* __restrict__ B,   // Bm [4096][512]
    const float* __restrict__ bias,
    float* __restrict__ out,
    int gm)                                 // M/128
{
    __shared__ __align__(16) unsigned short As[3][128 * 64];  // 48 KiB
    __shared__ __align__(16) unsigned short Bs[3][256 * 64];  // 96 KiB
    const int t = threadIdx.x;
    // bijective XCD swizzle (gridDim.x % 8 == 0): chunk-per-XCD
    const int nwg8 = gridDim.x >> 3;
    const int wg = (blockIdx.x & 7) * nwg8 + (blockIdx.x >> 3);
    const int mt = wg % gm;                 // m-fastest within chunk
    const int nt = wg / gm;
    const size_t r0 = (size_t)mt * 128;
    const size_t n0 = (size_t)nt * 256;
    const int lane = t & 63, w = t >> 6;
    const int wr = (w >> 2) * 64;           // wave m-origin  (2 groups)
    const int wc = (w & 3) * 64;            // wave n-origin  (4 groups)
    const int ml = lane & 15, kq = lane >> 4;

    const unsigned short* Ab = A + r0 * 512;
    const unsigned short* Bb = B + n0 * 512;

#define STAGE_TILE(b, kt)  do {                                              \
        const int kc_ = (kt) * 64;                                           \
        _Pragma("unroll")                                                    \
        for (int i_ = 0; i_ < 2; ++i_) {                                     \
            const int c_ = t + 512 * i_;                                     \
            const int row_ = c_ >> 3, sl_ = c_ & 7;                          \
            const int sg_ = sl_ ^ (row_ & 7);                                \
            gld16(Ab + (size_t)row_ * 512 + kc_ + sg_ * 8, As[b] + c_ * 8);  \
        }                                                                    \
        _Pragma("unroll")                                                    \
        for (int i_ = 0; i_ < 4; ++i_) {                                     \
            const int c_ = t + 512 * i_;                                     \
            const int row_ = c_ >> 3, sl_ = c_ & 7;                          \
            const int sg_ = sl_ ^ (row_ & 7);                                \
            gld16(Bb + (size_t)row_ * 512 + kc_ + sg_ * 8, Bs[b] + c_ * 8);  \
        }                                                                    \
    } while (0)

    for (int rep = 0; rep < REP_G; ++rep) {
    f32x4 acc[4][4];
#pragma unroll
    for (int m = 0; m < 4; ++m)
#pragma unroll
        for (int n = 0; n < 4; ++n) acc[m][n] = (f32x4){0.f, 0.f, 0.f, 0.f};

    // prologue: tiles 0 and 1 in flight (12 loads/thread)
    STAGE_TILE(0, 0);
    STAGE_TILE(1, 1);

    for (int kt = 0; kt < 8; ++kt) {
        __builtin_amdgcn_sched_barrier(0);
        if (kt < 7) asm volatile("s_waitcnt vmcnt(6) lgkmcnt(0)" ::: "memory");
        else        asm volatile("s_waitcnt vmcnt(0) lgkmcnt(0)" ::: "memory");
        __builtin_amdgcn_s_barrier();
        __builtin_amdgcn_sched_barrier(0);

        if (kt < 6) {
            const int nb = (kt + 2) % 3;
            STAGE_TILE(nb, kt + 2);
        }
        __builtin_amdgcn_sched_barrier(0);

        const unsigned short* Ax = As[kt % 3];
        const unsigned short* Bx = Bs[kt % 3];
#pragma unroll
        for (int ks = 0; ks < 2; ++ks) {
            bf16x8 af[4], bv[4];
#pragma unroll
            for (int m = 0; m < 4; ++m) {
                const int row = wr + m * 16 + ml;
                af[m] = *(const bf16x8*)(Ax + row * 64 + ((((ks << 2) + kq)) ^ (row & 7)) * 8);
            }
#pragma unroll
            for (int n = 0; n < 4; ++n) {
                const int row = wc + n * 16 + ml;
                bv[n] = *(const bf16x8*)(Bx + row * 64 + ((((ks << 2) + kq)) ^ (row & 7)) * 8);
            }
            __builtin_amdgcn_s_setprio(1);
#pragma unroll
            for (int m = 0; m < 4; ++m)
#pragma unroll
                for (int n = 0; n < 4; ++n)
                    acc[m][n] = __builtin_amdgcn_mfma_f32_16x16x32_bf16(af[m], bv[n], acc[m][n], 0, 0, 0);
            __builtin_amdgcn_s_setprio(0);
        }
    }

    // epilogue: D layout col=lane&15, row=(lane>>4)*4+r. Store + bias.
#pragma unroll
    for (int n = 0; n < 4; ++n) {
        const size_t col = n0 + wc + n * 16 + ml;
        const float bval = bias[col];
#pragma unroll
        for (int m = 0; m < 4; ++m) {
            const size_t rowb = r0 + wr + m * 16 + kq * 4;
#pragma unroll
            for (int r = 0; r < 4; ++r)
                out[(rowb + r) * DOUT + col] = acc[m][n][r] + bval;
        }
    }
    __syncthreads();   // protect LDS ring reuse across reps
    }
#undef STAGE_TILE
}

extern "C" void kernel_launch(void* const* d_in, const int* in_sizes, int n_in,
                              void* d_out, int out_size, void* d_ws, size_t ws_size,
                              hipStream_t stream) {
    const float* x    = (const float*)d_in[0];
    const float* core = (const float*)d_in[1];
    const float* fo0  = (const float*)d_in[2];
    const float* fo1  = (const float*)d_in[3];
    const float* fo2  = (const float*)d_in[4];
    const float* fi0  = (const float*)d_in[5];
    const float* fi1  = (const float*)d_in[6];
    const float* fi2  = (const float*)d_in[7];
    const float* bias = (const float*)d_in[8];
    const float* alpha= (const float*)d_in[9];
    const float* pds  = (const float*)d_in[10];
    const int* iperm  = (const int*)d_in[11];
    const int* oinv   = (const int*)d_in[12];
    float* out = (float*)d_out;

    const int nrows = in_sizes[0] / DIN;   // 8192

    unsigned short* Bm = (unsigned short*)d_ws;                       // 4 MiB
    unsigned short* t3 = (unsigned short*)d_ws + (2u << 20);          // 8 MiB @ +4 MiB

    tucker_kP<<<128, 256, 0, stream>>>(core, fo0, fo1, fo2, pds, alpha, oinv, Bm);
    tucker_kA<<<nrows, 256, 0, stream>>>(x, iperm, fi0, fi1, fi2, t3);
    const int gm = nrows / 128;            // 64
    tucker_kG<<<gm * (DOUT / 256), 512, 0, stream>>>(t3, Bm, bias, out, gm);
}

// Round 4
// 318.170 us; speedup vs baseline: 2.6937x; 2.6937x over previous
//
#include <hip/hip_runtime.h>
#include <hip/hip_bf16.h>

// TuckerLinear: out = ((x[:,iperm] @ W^T)[:,oinv]) * alpha * pds + bias
// W = (fo0 (x) fo1 (x) fo2) . G . (fi0 (x) fi1 (x) fi2)^T, G = core as 512x512.
//
// v5:
//  kP : fold output side into Bm[j][k] = alpha*pds[j]*(Fo_kron @ G)[oinv[j],k]  (bf16, ws)
//  kA : fp32 per-row x-gather + fi contractions -> t3 (bf16, ws)
//  kG : out = t3 @ Bm^T + bias, ring-3 pipelined MFMA GEMM (BM=128,BN=256,BK=64,
//       8 waves, counted vmcnt(6), XOR-swizzled LDS, XCD chunk swizzle) with
//       NON-TEMPORAL output stores: round-3 profiling showed FETCH_SIZE ~= |out|
//       per pass (L2 write-allocate RMW on partial-line stores) -> nt stores
//       eliminate the 134 MB/pass readback.
// Requires ws_size >= 12 MiB.

#define DIN 4096
#define DOUT 4096

typedef __bf16 bf16x8 __attribute__((ext_vector_type(8)));
typedef float f32x4 __attribute__((ext_vector_type(4)));

static __device__ __forceinline__ unsigned int f2bf(float f) {
    unsigned int u = __builtin_bit_cast(unsigned int, f);
    u += 0x7fffu + ((u >> 16) & 1u);     // round-to-nearest-even
    return u >> 16;
}

static __device__ __forceinline__ void gld16(const void* g, void* l) {
    __builtin_amdgcn_global_load_lds(
        (const __attribute__((address_space(1))) void*)g,
        (__attribute__((address_space(3))) void*)l, 16, 0, 0);
}

// ---------------------------------------------------------------------------
// kP: Bm[4096][512] bf16. 128 blocks, each owns 4 k-columns. 3-mode expansion
// of G's k-slice 512 -> 4096 rows in LDS, then row-gather by oinv + scale.
// ---------------------------------------------------------------------------
__global__ __launch_bounds__(256) void tucker_kP(
    const float* __restrict__ G,      // core as [512][512], row g=(a,b,c), col k=(d,e,f)
    const float* __restrict__ fo0,
    const float* __restrict__ fo1,
    const float* __restrict__ fo2,
    const float* __restrict__ pds,
    const float* __restrict__ alpha,
    const int*   __restrict__ oinv,
    unsigned short* __restrict__ Bm)  // ws: [4096][512] bf16
{
    __shared__ float Gk[512 * 4];     //  8 KB  [g][kk]
    __shared__ float W1[1024 * 4];    // 16 KB  [A*64+bc][kk]
    __shared__ float W2[2048 * 4];    // 32 KB  [(A*16+B)*8+c][kk]
    __shared__ float W3[4096 * 4];    // 64 KB  [o'][kk],  o' = A*256+B*16+C
    __shared__ float fos[3 * 128];
    const int t = threadIdx.x;
    const int k0 = blockIdx.x * 4;

    if (t < 128) {
        fos[t]       = fo0[t];
        fos[128 + t] = fo1[t];
        fos[256 + t] = fo2[t];
    }
#pragma unroll
    for (int i = 0; i < 2; ++i) {
        const int g = t + 256 * i;
        *(float4*)(Gk + g * 4) = *(const float4*)(G + (size_t)g * 512 + k0);
    }
    __syncthreads();

    // W1[A][bc] = sum_a fo0[A,a] * Gk[a*64+bc]
#pragma unroll
    for (int i = 0; i < 4; ++i) {
        const int o = t + 256 * i;            // 0..1023
        const int A = o >> 6, bc = o & 63;
        float4 acc = make_float4(0.f, 0.f, 0.f, 0.f);
#pragma unroll
        for (int a = 0; a < 8; ++a) {
            const float f = fos[A * 8 + a];
            const float4 g4 = *(const float4*)(Gk + (a * 64 + bc) * 4);
            acc.x += f * g4.x; acc.y += f * g4.y; acc.z += f * g4.z; acc.w += f * g4.w;
        }
        *(float4*)(W1 + o * 4) = acc;
    }
    __syncthreads();

    // W2[(A*16+B)*8+c] = sum_b fo1[B,b] * W1[A*64 + b*8 + c]
#pragma unroll
    for (int i = 0; i < 8; ++i) {
        const int o = t + 256 * i;            // 0..2047
        const int A = o >> 7, B = (o >> 3) & 15, c = o & 7;
        float4 acc = make_float4(0.f, 0.f, 0.f, 0.f);
#pragma unroll
        for (int b = 0; b < 8; ++b) {
            const float f = fos[128 + B * 8 + b];
            const float4 g4 = *(const float4*)(W1 + (A * 64 + b * 8 + c) * 4);
            acc.x += f * g4.x; acc.y += f * g4.y; acc.z += f * g4.z; acc.w += f * g4.w;
        }
        *(float4*)(W2 + o * 4) = acc;
    }
    __syncthreads();

    // W3[A*256+B*16+C] = sum_c fo2[C,c] * W2[(A*16+B)*8+c]
#pragma unroll
    for (int i = 0; i < 16; ++i) {
        const int o = t + 256 * i;            // 0..4095
        const int A = o >> 8, B = (o >> 4) & 15, C = o & 15;
        float4 acc = make_float4(0.f, 0.f, 0.f, 0.f);
#pragma unroll
        for (int c = 0; c < 8; ++c) {
            const float f = fos[256 + C * 8 + c];
            const float4 g4 = *(const float4*)(W2 + ((A * 16 + B) * 8 + c) * 4);
            acc.x += f * g4.x; acc.y += f * g4.y; acc.z += f * g4.z; acc.w += f * g4.w;
        }
        *(float4*)(W3 + o * 4) = acc;
    }
    __syncthreads();

    const float alf = alpha[0];
#pragma unroll
    for (int i = 0; i < 16; ++i) {
        const int j = t + 256 * i;
        const float s = alf * pds[j];
        const float4 v = *(const float4*)(W3 + (size_t)oinv[j] * 4);
        uint2 pk;
        pk.x = f2bf(v.x * s) | (f2bf(v.y * s) << 16);
        pk.y = f2bf(v.z * s) | (f2bf(v.w * s) << 16);
        *(uint2*)(Bm + (size_t)j * 512 + k0) = pk;
    }
}

// ---------------------------------------------------------------------------
// kA: per-row x-gather + fi contractions -> t3 (bf16) into ws.
// ---------------------------------------------------------------------------
__global__ __launch_bounds__(256) void tucker_kA(
    const float* __restrict__ x,
    const int*   __restrict__ iperm,
    const float* __restrict__ fi0,
    const float* __restrict__ fi1,
    const float* __restrict__ fi2,
    unsigned short* __restrict__ t3o)  // ws: [nrows][512] bf16
{
    __shared__ float xs[4096];         // 16 KB staged x row
    __shared__ float t1[8 * 272];      // [d][E*16+F], d-stride 272 -> 2-way (free)
    __shared__ float t2[8 * 136];      // [d*136 + e*17 + F] -> 2-way (free)
    const int t = threadIdx.x;
    const int n = blockIdx.x;

    {
        const float4* x4 = (const float4*)(x + (size_t)n * DIN);
        float4* xs4 = (float4*)xs;
#pragma unroll
        for (int i = 0; i < 4; ++i) xs4[t + 256 * i] = x4[t + 256 * i];
    }
    __syncthreads();

    // phase 1: t1[d,E,F] = sum_D xs[perm[D,E,F]] * fi0[D,d]   (t = E*16+F)
    {
        float acc[8];
#pragma unroll
        for (int d = 0; d < 8; ++d) acc[d] = 0.f;
#pragma unroll 4
        for (int D = 0; D < 16; ++D) {
            const int pg = iperm[D * 256 + t];
            const float v = xs[pg];
#pragma unroll
            for (int d = 0; d < 8; ++d) acc[d] += v * fi0[D * 8 + d];
        }
#pragma unroll
        for (int d = 0; d < 8; ++d) t1[d * 272 + t] = acc[d];
    }
    __syncthreads();

    // phase 2: t2[d,e,F] = sum_E t1[d,E,F] * fi1[E,e]
    if (t < 128) {
        const int d = t >> 4, F = t & 15;
        float acc[8];
#pragma unroll
        for (int e = 0; e < 8; ++e) acc[e] = 0.f;
#pragma unroll 4
        for (int E = 0; E < 16; ++E) {
            const float v = t1[d * 272 + E * 16 + F];
#pragma unroll
            for (int e = 0; e < 8; ++e) acc[e] += v * fi1[E * 8 + e];
        }
#pragma unroll
        for (int e = 0; e < 8; ++e) t2[d * 136 + e * 17 + F] = acc[e];
    }
    __syncthreads();

    // phase 3: t3[d,e,f] = sum_F t2[d,e,F] * fi2[F,f]; write bf16-packed
    if (t < 64) {
        const int d = t >> 3, e = t & 7;
        float acc[8];
#pragma unroll
        for (int f = 0; f < 8; ++f) acc[f] = 0.f;
#pragma unroll 4
        for (int F = 0; F < 16; ++F) {
            const float v = t2[d * 136 + e * 17 + F];
#pragma unroll
            for (int f = 0; f < 8; ++f) acc[f] += v * fi2[F * 8 + f];
        }
        uint4 pk;
        pk.x = f2bf(acc[0]) | (f2bf(acc[1]) << 16);
        pk.y = f2bf(acc[2]) | (f2bf(acc[3]) << 16);
        pk.z = f2bf(acc[4]) | (f2bf(acc[5]) << 16);
        pk.w = f2bf(acc[6]) | (f2bf(acc[7]) << 16);
        *(uint4*)(t3o + (size_t)n * 512 + t * 8) = pk;
    }
}

// ---------------------------------------------------------------------------
// kG: out[M][4096] = t3[M][512] @ Bm[4096][512]^T + bias.
// BM=128, BN=256, BK=64, 512 threads (8 waves, 2m x 4n, 64x64 wave tiles).
// Ring-3 LDS pipeline (144 KiB), counted s_waitcnt vmcnt(6), XOR-swizzled
// ds_read_b128, bijective XCD chunk swizzle, NON-TEMPORAL out stores.
// ---------------------------------------------------------------------------
__global__ __launch_bounds__(512) void tucker_kG(
    const unsigned short* __restrict__ A,   // t3 [M][512]
    const unsigned short* __restrict__ B,   // Bm [4096][512]
    const float* __restrict__ bias,
    float* __restrict__ out,
    int gm)                                 // M/128
{
    __shared__ __align__(16) unsigned short As[3][128 * 64];  // 48 KiB
    __shared__ __align__(16) unsigned short Bs[3][256 * 64];  // 96 KiB
    const int t = threadIdx.x;
    // bijective XCD swizzle (gridDim.x % 8 == 0): chunk-per-XCD
    const int nwg8 = gridDim.x >> 3;
    const int wg = (blockIdx.x & 7) * nwg8 + (blockIdx.x >> 3);
    const int mt = wg % gm;                 // m-fastest within chunk
    const int nt = wg / gm;
    const size_t r0 = (size_t)mt * 128;
    const size_t n0 = (size_t)nt * 256;
    const int lane = t & 63, w = t >> 6;
    const int wr = (w >> 2) * 64;           // wave m-origin  (2 groups)
    const int wc = (w & 3) * 64;            // wave n-origin  (4 groups)
    const int ml = lane & 15, kq = lane >> 4;

    const unsigned short* Ab = A + r0 * 512;
    const unsigned short* Bb = B + n0 * 512;

#define STAGE_TILE(b, kt)  do {                                              \
        const int kc_ = (kt) * 64;                                           \
        _Pragma("unroll")                                                    \
        for (int i_ = 0; i_ < 2; ++i_) {                                     \
            const int c_ = t + 512 * i_;                                     \
            const int row_ = c_ >> 3, sl_ = c_ & 7;                          \
            const int sg_ = sl_ ^ (row_ & 7);                                \
            gld16(Ab + (size_t)row_ * 512 + kc_ + sg_ * 8, As[b] + c_ * 8);  \
        }                                                                    \
        _Pragma("unroll")                                                    \
        for (int i_ = 0; i_ < 4; ++i_) {                                     \
            const int c_ = t + 512 * i_;                                     \
            const int row_ = c_ >> 3, sl_ = c_ & 7;                          \
            const int sg_ = sl_ ^ (row_ & 7);                                \
            gld16(Bb + (size_t)row_ * 512 + kc_ + sg_ * 8, Bs[b] + c_ * 8);  \
        }                                                                    \
    } while (0)

    f32x4 acc[4][4];
#pragma unroll
    for (int m = 0; m < 4; ++m)
#pragma unroll
        for (int n = 0; n < 4; ++n) acc[m][n] = (f32x4){0.f, 0.f, 0.f, 0.f};

    // prologue: tiles 0 and 1 in flight (12 loads/thread)
    STAGE_TILE(0, 0);
    STAGE_TILE(1, 1);

    for (int kt = 0; kt < 8; ++kt) {
        __builtin_amdgcn_sched_barrier(0);
        if (kt < 7) asm volatile("s_waitcnt vmcnt(6) lgkmcnt(0)" ::: "memory");
        else        asm volatile("s_waitcnt vmcnt(0) lgkmcnt(0)" ::: "memory");
        __builtin_amdgcn_s_barrier();
        __builtin_amdgcn_sched_barrier(0);

        if (kt < 6) {
            const int nb = (kt + 2) % 3;
            STAGE_TILE(nb, kt + 2);
        }
        __builtin_amdgcn_sched_barrier(0);

        const unsigned short* Ax = As[kt % 3];
        const unsigned short* Bx = Bs[kt % 3];
#pragma unroll
        for (int ks = 0; ks < 2; ++ks) {
            bf16x8 af[4], bv[4];
#pragma unroll
            for (int m = 0; m < 4; ++m) {
                const int row = wr + m * 16 + ml;
                af[m] = *(const bf16x8*)(Ax + row * 64 + ((((ks << 2) + kq)) ^ (row & 7)) * 8);
            }
#pragma unroll
            for (int n = 0; n < 4; ++n) {
                const int row = wc + n * 16 + ml;
                bv[n] = *(const bf16x8*)(Bx + row * 64 + ((((ks << 2) + kq)) ^ (row & 7)) * 8);
            }
            __builtin_amdgcn_s_setprio(1);
#pragma unroll
            for (int m = 0; m < 4; ++m)
#pragma unroll
                for (int n = 0; n < 4; ++n)
                    acc[m][n] = __builtin_amdgcn_mfma_f32_16x16x32_bf16(af[m], bv[n], acc[m][n], 0, 0, 0);
            __builtin_amdgcn_s_setprio(0);
        }
    }
#undef STAGE_TILE

    // epilogue: D layout col=lane&15, row=(lane>>4)*4+r. Non-temporal stores:
    // avoids L2 write-allocate RMW fetch of the 128 MiB output (round-3 PMC).
#pragma unroll
    for (int n = 0; n < 4; ++n) {
        const size_t col = n0 + wc + n * 16 + ml;
        const float bval = bias[col];
#pragma unroll
        for (int m = 0; m < 4; ++m) {
            const size_t rowb = r0 + wr + m * 16 + kq * 4;
#pragma unroll
            for (int r = 0; r < 4; ++r) {
                const float v = acc[m][n][r] + bval;
                __builtin_nontemporal_store(v, &out[(rowb + r) * DOUT + col]);
            }
        }
    }
}

extern "C" void kernel_launch(void* const* d_in, const int* in_sizes, int n_in,
                              void* d_out, int out_size, void* d_ws, size_t ws_size,
                              hipStream_t stream) {
    const float* x    = (const float*)d_in[0];
    const float* core = (const float*)d_in[1];
    const float* fo0  = (const float*)d_in[2];
    const float* fo1  = (const float*)d_in[3];
    const float* fo2  = (const float*)d_in[4];
    const float* fi0  = (const float*)d_in[5];
    const float* fi1  = (const float*)d_in[6];
    const float* fi2  = (const float*)d_in[7];
    const float* bias = (const float*)d_in[8];
    const float* alpha= (const float*)d_in[9];
    const float* pds  = (const float*)d_in[10];
    const int* iperm  = (const int*)d_in[11];
    const int* oinv   = (const int*)d_in[12];
    float* out = (float*)d_out;

    const int nrows = in_sizes[0] / DIN;   // 8192

    unsigned short* Bm = (unsigned short*)d_ws;                       // 4 MiB
    unsigned short* t3 = (unsigned short*)d_ws + (2u << 20);          // 8 MiB @ +4 MiB

    tucker_kP<<<128, 256, 0, stream>>>(core, fo0, fo1, fo2, pds, alpha, oinv, Bm);
    tucker_kA<<<nrows, 256, 0, stream>>>(x, iperm, fi0, fi1, fi2, t3);
    const int gm = nrows / 128;            // 64
    tucker_kG<<<gm * (DOUT / 256), 512, 0, stream>>>(t3, Bm, bias, out, gm);
}